// Round 1
// baseline (2019.137 us; speedup 1.0000x reference)
//
#include <hip/hip_runtime.h>

#define D 128

// ---------------------------------------------------------------- utilities

__global__ void zero_u32(unsigned int* p, long n) {
    long i = (long)blockIdx.x * blockDim.x + threadIdx.x;
    long stride = (long)gridDim.x * blockDim.x;
    for (; i < n; i += stride) p[i] = 0u;
}

// ---------------------------------------------------------------- CSR build

__global__ void count_deg(const int* __restrict__ dst, int* __restrict__ deg, int E) {
    int i = blockIdx.x * blockDim.x + threadIdx.x;
    int stride = gridDim.x * blockDim.x;
    for (; i < E; i += stride) atomicAdd(&deg[dst[i]], 1);
}

// Single-block exclusive scan of deg[0..n) -> rowptr[0..n], also copy to cursor.
__global__ __launch_bounds__(1024)
void scan_deg(const int* __restrict__ deg, int* __restrict__ rowptr,
              int* __restrict__ cursor, int n) {
    __shared__ int ssum[1024];
    int t = threadIdx.x;
    int chunk = (n + 1023) / 1024;
    int begin = t * chunk;
    int end = begin + chunk; if (end > n) end = n; if (begin > n) begin = n;
    int s = 0;
    for (int i = begin; i < end; ++i) s += deg[i];
    ssum[t] = s;
    __syncthreads();
    for (int off = 1; off < 1024; off <<= 1) {
        int v = 0;
        if (t >= off) v = ssum[t - off];
        __syncthreads();
        ssum[t] += v;
        __syncthreads();
    }
    int run = (t == 0) ? 0 : ssum[t - 1];
    for (int i = begin; i < end; ++i) {
        int d = deg[i];          // read before overwrite (deg may alias cursor)
        rowptr[i] = run;
        cursor[i] = run;
        run += d;
    }
    if (t == 1023) rowptr[n] = ssum[1023];
}

__global__ void fill_csr(const int* __restrict__ src, const int* __restrict__ dst,
                         int* __restrict__ cursor, int* __restrict__ csr_src, int E) {
    int i = blockIdx.x * blockDim.x + threadIdx.x;
    int stride = gridDim.x * blockDim.x;
    for (; i < E; i += stride) {
        int p = atomicAdd(&cursor[dst[i]], 1);
        csr_src[p] = src[i];
    }
}

// ---------------------------------------------------------------- small reductions

// h_lead[d] = sum_r lead[r][d]   (1 block, 128 threads)
__global__ void reduce_lead(const float* __restrict__ lead, float* __restrict__ hlead, int NL) {
    int d = threadIdx.x;
    float s = 0.f;
    for (int r = 0; r < NL; ++r) s += lead[(long)r * D + d];
    hlead[d] = s;
}

__global__ void add_lead(float* __restrict__ ctx, const float* __restrict__ hlead, int n) {
    int i = blockIdx.x * blockDim.x + threadIdx.x;
    int stride = gridDim.x * blockDim.x;
    for (; i < n; i += stride) ctx[i] += hlead[i & (D - 1)];
}

// segment sum of feat[n][D] by sorted gids into out[G][D] (out must be zeroed).
// One wave (64 threads) per 128-row chunk; atomics only at segment boundaries.
__global__ __launch_bounds__(64)
void segsum(const float* __restrict__ feat, const int* __restrict__ gids,
            float* __restrict__ out, int n) {
    int lane = threadIdx.x;
    int r0 = blockIdx.x * 128;
    if (r0 >= n) return;
    int r1 = r0 + 128; if (r1 > n) r1 = n;
    float2 acc = make_float2(0.f, 0.f);
    int cur = gids[r0];
    for (int r = r0; r < r1; ++r) {
        int g = gids[r];
        if (g != cur) {
            atomicAdd(&out[(long)cur * D + lane * 2], acc.x);
            atomicAdd(&out[(long)cur * D + lane * 2 + 1], acc.y);
            acc.x = 0.f; acc.y = 0.f;
            cur = g;
        }
        float2 v = *(const float2*)(feat + (long)r * D + lane * 2);
        acc.x += v.x; acc.y += v.y;
    }
    atomicAdd(&out[(long)cur * D + lane * 2], acc.x);
    atomicAdd(&out[(long)cur * D + lane * 2 + 1], acc.y);
}

// ---------------------------------------------------------------- per-graph row matmul
// out[g][d] = (relu?)( X[g]@Wm[:,d] + (X2 ? X2[g]@W2[:,d] : 0) + bias[d] )
__global__ __launch_bounds__(128)
void rowmat(const float* __restrict__ X, const float* __restrict__ Wm,
            const float* __restrict__ bias,
            const float* __restrict__ X2, const float* __restrict__ W2,
            float* __restrict__ out, int do_relu) {
    __shared__ float xs[D];
    __shared__ float xs2[D];
    int g = blockIdx.x;
    int d = threadIdx.x;
    xs[d] = X[(long)g * D + d];
    if (X2) xs2[d] = X2[(long)g * D + d];
    __syncthreads();
    float acc = bias ? bias[d] : 0.f;
    #pragma unroll 4
    for (int k = 0; k < D; ++k) acc += xs[k] * Wm[(long)k * D + d];
    if (X2) {
        #pragma unroll 4
        for (int k = 0; k < D; ++k) acc += xs2[k] * W2[(long)k * D + d];
    }
    out[(long)g * D + d] = do_relu ? fmaxf(acc, 0.f) : acc;
}

// ---------------------------------------------------------------- fused GIN layer
// h_out[r] = relu( ((1+eps)h[r] + sum_{nbr} h[nbr]) @ W  +  T[gid[r]] )
#define TROWS 64
__global__ __launch_bounds__(256)
void layer_kernel(const float* __restrict__ h, const float* __restrict__ Wl,
                  const float* __restrict__ T, const int* __restrict__ gids,
                  const int* __restrict__ rowptr, const int* __restrict__ csr_src,
                  const float* __restrict__ eps_l, float* __restrict__ hout, int n) {
    __shared__ float Min[TROWS][D];
    int t = threadIdx.x;
    int wave = t >> 6, lane = t & 63;
    int rowBase = blockIdx.x * TROWS;
    float epsv = 1.0f + *eps_l;

    // Phase 1: CSR gather + self term into LDS. Wave w handles rows w*16..w*16+15.
    for (int i = 0; i < 16; ++i) {
        int rl = wave * 16 + i;
        int r = rowBase + rl;
        float2 acc = make_float2(0.f, 0.f);
        if (r < n) {
            float2 v = *(const float2*)(h + (long)r * D + lane * 2);
            acc.x = epsv * v.x; acc.y = epsv * v.y;
            int e0 = rowptr[r], e1 = rowptr[r + 1];
            for (int e = e0; e < e1; ++e) {
                int s = csr_src[e];
                float2 u = *(const float2*)(h + (long)s * D + lane * 2);
                acc.x += u.x; acc.y += u.y;
            }
        }
        *(float2*)&Min[rl][lane * 2] = acc;
    }
    __syncthreads();

    // Phase 2: 64x128 tile matmul. Thread: rows r0..r0+7, cols c0..c0+3.
    int ty = t >> 5, tx = t & 31;
    int r0 = ty * 8, c0 = tx * 4;
    float acc[8][4];
    #pragma unroll
    for (int j = 0; j < 8; ++j)
        #pragma unroll
        for (int q = 0; q < 4; ++q) acc[j][q] = 0.f;

    for (int k = 0; k < D; k += 4) {
        float a_[8][4];
        #pragma unroll
        for (int j = 0; j < 8; ++j)
            *(float4*)a_[j] = *(const float4*)&Min[r0 + j][k];
        #pragma unroll
        for (int kk = 0; kk < 4; ++kk) {
            float4 wv = *(const float4*)(Wl + (long)(k + kk) * D + c0);
            #pragma unroll
            for (int j = 0; j < 8; ++j) {
                float av = a_[j][kk];
                acc[j][0] += av * wv.x;
                acc[j][1] += av * wv.y;
                acc[j][2] += av * wv.z;
                acc[j][3] += av * wv.w;
            }
        }
    }

    // Phase 3: add per-graph term, relu, store.
    #pragma unroll
    for (int j = 0; j < 8; ++j) {
        int r = rowBase + r0 + j;
        if (r < n) {
            int g = gids[r];
            float4 tv = *(const float4*)(T + (long)g * D + c0);
            float4 o;
            o.x = fmaxf(acc[j][0] + tv.x, 0.f);
            o.y = fmaxf(acc[j][1] + tv.y, 0.f);
            o.z = fmaxf(acc[j][2] + tv.z, 0.f);
            o.w = fmaxf(acc[j][3] + tv.w, 0.f);
            *(float4*)(hout + (long)r * D + c0) = o;
        }
    }
}

// ---------------------------------------------------------------- launch

static inline size_t align512(size_t x) { return (x + 511) & ~(size_t)511; }

extern "C" void kernel_launch(void* const* d_in, const int* in_sizes, int n_in,
                              void* d_out, int out_size, void* d_ws, size_t ws_size,
                              hipStream_t stream) {
    const float* x        = (const float*)d_in[0];
    const int*   src      = (const int*)d_in[1];
    const int*   dst      = (const int*)d_in[2];
    const int*   gids     = (const int*)d_in[3];
    const float* initf    = (const float*)d_in[4];
    const int*   init_gid = (const int*)d_in[5];
    const float* leadf    = (const float*)d_in[6];
    const float* W        = (const float*)d_in[7];
    const float* Wc       = (const float*)d_in[8];
    const float* b        = (const float*)d_in[9];
    const float* eps      = (const float*)d_in[10];
    const float* fc1_w    = (const float*)d_in[11];
    const float* fc1_b    = (const float*)d_in[12];
    const float* fc2_w    = (const float*)d_in[13];
    const float* fc2_b    = (const float*)d_in[14];
    float* out = (float*)d_out;

    const int N  = in_sizes[0] / D;
    const int E  = in_sizes[1];
    const int NI = in_sizes[4] / D;
    const int NL = in_sizes[6] / D;
    const int L  = in_sizes[10];
    const int C  = in_sizes[13] / D;
    const int G  = out_size / C;

    // workspace carve-up
    char* p = (char*)d_ws;
    float* hA   = (float*)p; p += align512((size_t)N * D * 4);
    float* hB   = (float*)p; p += align512((size_t)N * D * 4);
    float* hg   = (float*)p; p += align512((size_t)G * D * 4);
    float* T    = (float*)p; p += align512((size_t)G * D * 4);
    float* ctx  = (float*)p; p += align512((size_t)G * D * 4);
    float* z    = (float*)p; p += align512((size_t)G * D * 4);
    float* hlead= (float*)p; p += align512((size_t)D * 4);
    int* rowptr = (int*)p;   p += align512((size_t)(N + 1) * 4);
    int* cursor = (int*)p;   p += align512((size_t)N * 4);
    int* csr    = (int*)p;   p += align512((size_t)E * 4);
    (void)ws_size; (void)n_in;

    // ---- CSR build (once per call; reused across layers)
    zero_u32<<<512, 256, 0, stream>>>((unsigned int*)cursor, N);
    count_deg<<<1024, 256, 0, stream>>>(dst, cursor, E);
    scan_deg<<<1, 1024, 0, stream>>>(cursor, rowptr, cursor, N);
    fill_csr<<<1024, 256, 0, stream>>>(src, dst, cursor, csr, E);

    // ---- global context ctx_g[g] = segsum(init_feat) + h_lead
    reduce_lead<<<1, D, 0, stream>>>(leadf, hlead, NL);
    zero_u32<<<256, 256, 0, stream>>>((unsigned int*)ctx, (long)G * D);
    segsum<<<(NI + 127) / 128, 64, 0, stream>>>(initf, init_gid, ctx, NI);
    add_lead<<<256, 256, 0, stream>>>(ctx, hlead, G * D);

    // ---- initial h_global from x
    zero_u32<<<256, 256, 0, stream>>>((unsigned int*)hg, (long)G * D);
    segsum<<<(N + 127) / 128, 64, 0, stream>>>(x, gids, hg, N);

    const float* hcur = x;
    float* bufs[2] = { hA, hB };
    int layerBlocks = (N + TROWS - 1) / TROWS;
    for (int l = 0; l < L; ++l) {
        // per-graph term: T = hg@W[l] + ctx@Wc[l] + b[l]
        rowmat<<<G, D, 0, stream>>>(hg, W + (long)l * D * D, b + (long)l * D,
                                    ctx, Wc + (long)l * D * D, T, 0);
        float* hnext = bufs[l & 1];
        layer_kernel<<<layerBlocks, 256, 0, stream>>>(hcur, W + (long)l * D * D, T,
                                                      gids, rowptr, csr,
                                                      eps + l, hnext, N);
        zero_u32<<<256, 256, 0, stream>>>((unsigned int*)hg, (long)G * D);
        segsum<<<(N + 127) / 128, 64, 0, stream>>>(hnext, gids, hg, N);
        hcur = hnext;
    }

    // ---- readout: out = relu(hg@fc1 + fc1_b) @ fc2 + fc2_b
    rowmat<<<G, D, 0, stream>>>(hg, fc1_w, fc1_b, (const float*)nullptr,
                                (const float*)nullptr, z, 1);
    rowmat<<<G, C, 0, stream>>>(z, fc2_w, fc2_b, (const float*)nullptr,
                                (const float*)nullptr, out, 0);
}

// Round 2
// 1272.883 us; speedup vs baseline: 1.5863x; 1.5863x over previous
//
#include <hip/hip_runtime.h>

#define D 128

// ---------------------------------------------------------------- utilities

__global__ void zero_u32(unsigned int* p, long n) {
    long i = (long)blockIdx.x * blockDim.x + threadIdx.x;
    long stride = (long)gridDim.x * blockDim.x;
    for (; i < n; i += stride) p[i] = 0u;
}

// ---------------------------------------------------------------- CSR build

__global__ void count_deg(const int* __restrict__ dst, int* __restrict__ deg, int E) {
    int i = blockIdx.x * blockDim.x + threadIdx.x;
    int stride = gridDim.x * blockDim.x;
    for (; i < E; i += stride) atomicAdd(&deg[dst[i]], 1);
}

// Single-block exclusive scan of deg[0..n) -> rowptr[0..n], also copy to cursor.
__global__ __launch_bounds__(1024)
void scan_deg(const int* __restrict__ deg, int* __restrict__ rowptr,
              int* __restrict__ cursor, int n) {
    __shared__ int ssum[1024];
    int t = threadIdx.x;
    int chunk = (n + 1023) / 1024;
    int begin = t * chunk;
    int end = begin + chunk; if (end > n) end = n; if (begin > n) begin = n;
    int s = 0;
    for (int i = begin; i < end; ++i) s += deg[i];
    ssum[t] = s;
    __syncthreads();
    for (int off = 1; off < 1024; off <<= 1) {
        int v = 0;
        if (t >= off) v = ssum[t - off];
        __syncthreads();
        ssum[t] += v;
        __syncthreads();
    }
    int run = (t == 0) ? 0 : ssum[t - 1];
    for (int i = begin; i < end; ++i) {
        int d = deg[i];          // read before overwrite (deg may alias cursor)
        rowptr[i] = run;
        cursor[i] = run;
        run += d;
    }
    if (t == 1023) rowptr[n] = ssum[1023];
}

__global__ void fill_csr(const int* __restrict__ src, const int* __restrict__ dst,
                         int* __restrict__ cursor, int* __restrict__ csr_src, int E) {
    int i = blockIdx.x * blockDim.x + threadIdx.x;
    int stride = gridDim.x * blockDim.x;
    for (; i < E; i += stride) {
        int p = atomicAdd(&cursor[dst[i]], 1);
        csr_src[p] = src[i];
    }
}

// ---------------------------------------------------------------- graph segment starts
// start[g] = first row index with gids[row] >= g (gids sorted); start[G]=n.
__global__ void find_starts(const int* __restrict__ gids, int n, int G_,
                            int* __restrict__ start) {
    int g = blockIdx.x * blockDim.x + threadIdx.x;
    if (g > G_) return;
    if (g == G_) { start[g] = n; return; }
    int lo = 0, hi = n;
    while (lo < hi) { int mid = (lo + hi) >> 1; if (gids[mid] < g) lo = mid + 1; else hi = mid; }
    start[g] = lo;
}

// ---------------------------------------------------------------- small reductions

// h_lead[d] = sum_r lead[r][d]   (1 block, 128 threads)
__global__ void reduce_lead(const float* __restrict__ lead, float* __restrict__ hlead, int NL) {
    int d = threadIdx.x;
    float a0 = 0.f, a1 = 0.f, a2 = 0.f, a3 = 0.f;
    int r = 0;
    for (; r + 4 <= NL; r += 4) {
        a0 += lead[(long)r * D + d];
        a1 += lead[(long)(r + 1) * D + d];
        a2 += lead[(long)(r + 2) * D + d];
        a3 += lead[(long)(r + 3) * D + d];
    }
    for (; r < NL; ++r) a0 += lead[(long)r * D + d];
    hlead[d] = a0 + a1 + a2 + a3;
}

// per-graph segment sum: out[g][d] = sum_{r in [start[g],start[g+1])} feat[r][d] (+ addv[d])
__global__ __launch_bounds__(128)
void segsum_pg(const float* __restrict__ feat, const int* __restrict__ start,
               const float* __restrict__ addv, float* __restrict__ out) {
    int g = blockIdx.x;
    int d = threadIdx.x;
    int r0 = start[g], r1 = start[g + 1];
    float a0 = 0.f, a1 = 0.f, a2 = 0.f, a3 = 0.f;
    int r = r0;
    for (; r + 4 <= r1; r += 4) {
        a0 += feat[(long)r * D + d];
        a1 += feat[(long)(r + 1) * D + d];
        a2 += feat[(long)(r + 2) * D + d];
        a3 += feat[(long)(r + 3) * D + d];
    }
    for (; r < r1; ++r) a0 += feat[(long)r * D + d];
    float s = a0 + a1 + a2 + a3;
    if (addv) s += addv[d];
    out[(long)g * D + d] = s;
}

// ---------------------------------------------------------------- per-graph row matmul
// out[g][d] = (relu?)( X[g]@Wm[:,d] + (X2 ? X2[g]@W2[:,d] : 0) + bias[d] )
__global__ __launch_bounds__(128)
void rowmat(const float* __restrict__ X, const float* __restrict__ Wm,
            const float* __restrict__ bias,
            const float* __restrict__ X2, const float* __restrict__ W2,
            float* __restrict__ out, int do_relu) {
    __shared__ float xs[D];
    __shared__ float xs2[D];
    int g = blockIdx.x;
    int d = threadIdx.x;
    xs[d] = X[(long)g * D + d];
    if (X2) xs2[d] = X2[(long)g * D + d];
    __syncthreads();
    float acc = bias ? bias[d] : 0.f;
    #pragma unroll 8
    for (int k = 0; k < D; ++k) acc += xs[k] * Wm[(long)k * D + d];
    if (X2) {
        #pragma unroll 8
        for (int k = 0; k < D; ++k) acc += xs2[k] * W2[(long)k * D + d];
    }
    out[(long)g * D + d] = do_relu ? fmaxf(acc, 0.f) : acc;
}

// ---------------------------------------------------------------- fused GIN layer
// h_out[r] = relu( ((1+eps)h[r] + sum_{nbr} h[nbr]) @ W  +  T[gid[r]] )
#define TROWS 64
__global__ __launch_bounds__(256)
void layer_kernel(const float* __restrict__ h, const float* __restrict__ Wl,
                  const float* __restrict__ T, const int* __restrict__ gids,
                  const int* __restrict__ rowptr, const int* __restrict__ csr_src,
                  const float* __restrict__ eps_l, float* __restrict__ hout, int n) {
    __shared__ float Min[TROWS][D];
    int t = threadIdx.x;
    int wave = t >> 6, lane = t & 63;
    int rowBase = blockIdx.x * TROWS;
    float epsv = 1.0f + *eps_l;

    // Phase 1: CSR gather + self term into LDS. Wave w handles rows w*16..w*16+15.
    // 4 independent accumulator chains -> 4 outstanding gather loads per lane.
    for (int i = 0; i < 16; ++i) {
        int rl = wave * 16 + i;
        int r = rowBase + rl;
        float2 tot = make_float2(0.f, 0.f);
        if (r < n) {
            float2 v = *(const float2*)(h + (long)r * D + lane * 2);
            float2 a0 = make_float2(epsv * v.x, epsv * v.y);
            float2 a1 = make_float2(0.f, 0.f);
            float2 a2 = make_float2(0.f, 0.f);
            float2 a3 = make_float2(0.f, 0.f);
            int e = rowptr[r], e1 = rowptr[r + 1];
            for (; e + 4 <= e1; e += 4) {
                int s0 = csr_src[e];
                int s1 = csr_src[e + 1];
                int s2 = csr_src[e + 2];
                int s3 = csr_src[e + 3];
                float2 u0 = *(const float2*)(h + (long)s0 * D + lane * 2);
                float2 u1 = *(const float2*)(h + (long)s1 * D + lane * 2);
                float2 u2 = *(const float2*)(h + (long)s2 * D + lane * 2);
                float2 u3 = *(const float2*)(h + (long)s3 * D + lane * 2);
                a0.x += u0.x; a0.y += u0.y;
                a1.x += u1.x; a1.y += u1.y;
                a2.x += u2.x; a2.y += u2.y;
                a3.x += u3.x; a3.y += u3.y;
            }
            for (; e < e1; ++e) {
                int s = csr_src[e];
                float2 u = *(const float2*)(h + (long)s * D + lane * 2);
                a0.x += u.x; a0.y += u.y;
            }
            tot.x = (a0.x + a1.x) + (a2.x + a3.x);
            tot.y = (a0.y + a1.y) + (a2.y + a3.y);
        }
        *(float2*)&Min[rl][lane * 2] = tot;
    }
    __syncthreads();

    // Phase 2: 64x128 tile matmul. Thread: rows r0..r0+7, cols c0..c0+3.
    int ty = t >> 5, tx = t & 31;
    int r0 = ty * 8, c0 = tx * 4;
    float acc[8][4];
    #pragma unroll
    for (int j = 0; j < 8; ++j)
        #pragma unroll
        for (int q = 0; q < 4; ++q) acc[j][q] = 0.f;

    for (int k = 0; k < D; k += 4) {
        float a_[8][4];
        #pragma unroll
        for (int j = 0; j < 8; ++j)
            *(float4*)a_[j] = *(const float4*)&Min[r0 + j][k];
        #pragma unroll
        for (int kk = 0; kk < 4; ++kk) {
            float4 wv = *(const float4*)(Wl + (long)(k + kk) * D + c0);
            #pragma unroll
            for (int j = 0; j < 8; ++j) {
                float av = a_[j][kk];
                acc[j][0] += av * wv.x;
                acc[j][1] += av * wv.y;
                acc[j][2] += av * wv.z;
                acc[j][3] += av * wv.w;
            }
        }
    }

    // Phase 3: add per-graph term, relu, store.
    #pragma unroll
    for (int j = 0; j < 8; ++j) {
        int r = rowBase + r0 + j;
        if (r < n) {
            int g = gids[r];
            float4 tv = *(const float4*)(T + (long)g * D + c0);
            float4 o;
            o.x = fmaxf(acc[j][0] + tv.x, 0.f);
            o.y = fmaxf(acc[j][1] + tv.y, 0.f);
            o.z = fmaxf(acc[j][2] + tv.z, 0.f);
            o.w = fmaxf(acc[j][3] + tv.w, 0.f);
            *(float4*)(hout + (long)r * D + c0) = o;
        }
    }
}

// ---------------------------------------------------------------- launch

static inline size_t align512(size_t x) { return (x + 511) & ~(size_t)511; }

extern "C" void kernel_launch(void* const* d_in, const int* in_sizes, int n_in,
                              void* d_out, int out_size, void* d_ws, size_t ws_size,
                              hipStream_t stream) {
    const float* x        = (const float*)d_in[0];
    const int*   src      = (const int*)d_in[1];
    const int*   dst      = (const int*)d_in[2];
    const int*   gids     = (const int*)d_in[3];
    const float* initf    = (const float*)d_in[4];
    const int*   init_gid = (const int*)d_in[5];
    const float* leadf    = (const float*)d_in[6];
    const float* W        = (const float*)d_in[7];
    const float* Wc       = (const float*)d_in[8];
    const float* b        = (const float*)d_in[9];
    const float* eps      = (const float*)d_in[10];
    const float* fc1_w    = (const float*)d_in[11];
    const float* fc1_b    = (const float*)d_in[12];
    const float* fc2_w    = (const float*)d_in[13];
    const float* fc2_b    = (const float*)d_in[14];
    float* out = (float*)d_out;

    const int N  = in_sizes[0] / D;
    const int E  = in_sizes[1];
    const int NI = in_sizes[4] / D;
    const int NL = in_sizes[6] / D;
    const int L  = in_sizes[10];
    const int C  = in_sizes[13] / D;
    const int G  = out_size / C;

    // workspace carve-up
    char* p = (char*)d_ws;
    float* hA    = (float*)p; p += align512((size_t)N * D * 4);
    float* hB    = (float*)p; p += align512((size_t)N * D * 4);
    float* hg    = (float*)p; p += align512((size_t)G * D * 4);
    float* T     = (float*)p; p += align512((size_t)G * D * 4);
    float* ctx   = (float*)p; p += align512((size_t)G * D * 4);
    float* z     = (float*)p; p += align512((size_t)G * D * 4);
    float* hlead = (float*)p; p += align512((size_t)D * 4);
    int* rowptr  = (int*)p;   p += align512((size_t)(N + 1) * 4);
    int* cursor  = (int*)p;   p += align512((size_t)N * 4);
    int* csr     = (int*)p;   p += align512((size_t)E * 4);
    int* nstart  = (int*)p;   p += align512((size_t)(G + 1) * 4);
    int* istart  = (int*)p;   p += align512((size_t)(G + 1) * 4);
    (void)ws_size; (void)n_in;

    // ---- CSR build (once per call; reused across layers)
    zero_u32<<<512, 256, 0, stream>>>((unsigned int*)cursor, N);
    count_deg<<<1024, 256, 0, stream>>>(dst, cursor, E);
    scan_deg<<<1, 1024, 0, stream>>>(cursor, rowptr, cursor, N);
    fill_csr<<<1024, 256, 0, stream>>>(src, dst, cursor, csr, E);

    // ---- per-graph row ranges (sorted gids)
    find_starts<<<(G + 256) / 256, 256, 0, stream>>>(gids, N, G, nstart);
    find_starts<<<(G + 256) / 256, 256, 0, stream>>>(init_gid, NI, G, istart);

    // ---- global context ctx[g] = segsum(init_feat)[g] + h_lead
    reduce_lead<<<1, D, 0, stream>>>(leadf, hlead, NL);
    segsum_pg<<<G, D, 0, stream>>>(initf, istart, hlead, ctx);

    // ---- initial h_global from x
    segsum_pg<<<G, D, 0, stream>>>(x, nstart, (const float*)nullptr, hg);

    const float* hcur = x;
    float* bufs[2] = { hA, hB };
    int layerBlocks = (N + TROWS - 1) / TROWS;
    for (int l = 0; l < L; ++l) {
        // per-graph term: T = hg@W[l] + ctx@Wc[l] + b[l]
        rowmat<<<G, D, 0, stream>>>(hg, W + (long)l * D * D, b + (long)l * D,
                                    ctx, Wc + (long)l * D * D, T, 0);
        float* hnext = bufs[l & 1];
        layer_kernel<<<layerBlocks, 256, 0, stream>>>(hcur, W + (long)l * D * D, T,
                                                      gids, rowptr, csr,
                                                      eps + l, hnext, N);
        segsum_pg<<<G, D, 0, stream>>>(hnext, nstart, (const float*)nullptr, hg);
        hcur = hnext;
    }

    // ---- readout: out = relu(hg@fc1 + fc1_b) @ fc2 + fc2_b
    rowmat<<<G, D, 0, stream>>>(hg, fc1_w, fc1_b, (const float*)nullptr,
                                (const float*)nullptr, z, 1);
    rowmat<<<G, C, 0, stream>>>(z, fc2_w, fc2_b, (const float*)nullptr,
                                (const float*)nullptr, out, 0);
}

// Round 3
// 932.968 us; speedup vs baseline: 2.1642x; 1.3643x over previous
//
#include <hip/hip_runtime.h>

#define D 128

// ---------------------------------------------------------------- bf16 helpers
__device__ __forceinline__ float bf_lo(unsigned u) { return __uint_as_float(u << 16); }
__device__ __forceinline__ float bf_hi(unsigned u) { return __uint_as_float(u & 0xffff0000u); }
__device__ __forceinline__ unsigned to_bf1(float x) {           // RNE round to bf16 (low 16 bits)
    unsigned b = __float_as_uint(x);
    return (b + 0x7fffu + ((b >> 16) & 1u)) >> 16;
}
__device__ __forceinline__ unsigned pack2(float a, float b) {
    return to_bf1(a) | (to_bf1(b) << 16);
}

// ---------------------------------------------------------------- utilities

__global__ void zero_u32(unsigned int* p, long n) {
    long i = (long)blockIdx.x * blockDim.x + threadIdx.x;
    long stride = (long)gridDim.x * blockDim.x;
    for (; i < n; i += stride) p[i] = 0u;
}

__global__ void f32_to_bf16(const float4* __restrict__ in, uint2* __restrict__ out, long n4) {
    long i = (long)blockIdx.x * blockDim.x + threadIdx.x;
    long stride = (long)gridDim.x * blockDim.x;
    for (; i < n4; i += stride) {
        float4 v = in[i];
        out[i] = make_uint2(pack2(v.x, v.y), pack2(v.z, v.w));
    }
}

// ---------------------------------------------------------------- CSR build

__global__ void count_deg(const int* __restrict__ dst, int* __restrict__ deg, int E) {
    int i = blockIdx.x * blockDim.x + threadIdx.x;
    int stride = gridDim.x * blockDim.x;
    for (; i < E; i += stride) atomicAdd(&deg[dst[i]], 1);
}

#define SCHUNK 1024
// per-block partial sums of deg
__global__ __launch_bounds__(256)
void scan_part(const int* __restrict__ deg, int* __restrict__ psum, int n) {
    int b = blockIdx.x, t = threadIdx.x;
    int base = b * SCHUNK;
    int s = 0;
    for (int i = t; i < SCHUNK; i += 256) {
        int idx = base + i;
        if (idx < n) s += deg[idx];
    }
    for (int off = 32; off; off >>= 1) s += __shfl_down(s, off);
    __shared__ int ws[4];
    if ((t & 63) == 0) ws[t >> 6] = s;
    __syncthreads();
    if (t == 0) psum[b] = ws[0] + ws[1] + ws[2] + ws[3];
}

// exclusive scan of psum[0..nb) (nb <= 128), write total to rowptrN
__global__ __launch_bounds__(64)
void scan_psum(int* __restrict__ psum, int* __restrict__ rowptrN, int nb) {
    int lane = threadIdx.x;
    int v0 = (lane < nb) ? psum[lane] : 0;
    int v1 = (lane + 64 < nb) ? psum[lane + 64] : 0;
    int x = v0;
    for (int off = 1; off < 64; off <<= 1) { int y = __shfl_up(x, off); if (lane >= off) x += y; }
    int total0 = __shfl(x, 63);
    int x1 = v1;
    for (int off = 1; off < 64; off <<= 1) { int y = __shfl_up(x1, off); if (lane >= off) x1 += y; }
    if (lane < nb) psum[lane] = x - v0;
    if (lane + 64 < nb) psum[lane + 64] = total0 + x1 - v1;
    if (lane == 63) rowptrN[0] = total0 + x1;
}

// per-block exclusive scan + scatter; deg may alias cursor (each elem touched by owner thread only)
__global__ __launch_bounds__(256)
void scan_scatter(const int* __restrict__ deg, const int* __restrict__ psum,
                  int* __restrict__ rowptr, int* __restrict__ cursor, int n) {
    int b = blockIdx.x, t = threadIdx.x;
    int i0 = b * SCHUNK + t * 4;
    int d0 = 0, d1 = 0, d2 = 0, d3 = 0;
    if (i0     < n) d0 = deg[i0];
    if (i0 + 1 < n) d1 = deg[i0 + 1];
    if (i0 + 2 < n) d2 = deg[i0 + 2];
    if (i0 + 3 < n) d3 = deg[i0 + 3];
    int s = d0 + d1 + d2 + d3;
    __shared__ int sc[256];
    sc[t] = s; __syncthreads();
    for (int off = 1; off < 256; off <<= 1) {
        int v = (t >= off) ? sc[t - off] : 0;
        __syncthreads();
        sc[t] += v;
        __syncthreads();
    }
    int run = psum[b] + sc[t] - s;
    if (i0     < n) { rowptr[i0]     = run; cursor[i0]     = run; run += d0; }
    if (i0 + 1 < n) { rowptr[i0 + 1] = run; cursor[i0 + 1] = run; run += d1; }
    if (i0 + 2 < n) { rowptr[i0 + 2] = run; cursor[i0 + 2] = run; run += d2; }
    if (i0 + 3 < n) { rowptr[i0 + 3] = run; cursor[i0 + 3] = run; run += d3; }
}

__global__ void fill_csr(const int* __restrict__ src, const int* __restrict__ dst,
                         int* __restrict__ cursor, int* __restrict__ csr_src, int E) {
    int i = blockIdx.x * blockDim.x + threadIdx.x;
    int stride = gridDim.x * blockDim.x;
    for (; i < E; i += stride) {
        int p = atomicAdd(&cursor[dst[i]], 1);
        csr_src[p] = src[i];
    }
}

// ---------------------------------------------------------------- graph segment starts
__global__ void find_starts(const int* __restrict__ gids, int n, int G_,
                            int* __restrict__ start) {
    int g = blockIdx.x * blockDim.x + threadIdx.x;
    if (g > G_) return;
    if (g == G_) { start[g] = n; return; }
    int lo = 0, hi = n;
    while (lo < hi) { int mid = (lo + hi) >> 1; if (gids[mid] < g) lo = mid + 1; else hi = mid; }
    start[g] = lo;
}

// ---------------------------------------------------------------- reductions

__global__ void reduce_lead(const float* __restrict__ lead, float* __restrict__ hlead, int NL) {
    int d = threadIdx.x;
    float a0 = 0.f, a1 = 0.f, a2 = 0.f, a3 = 0.f;
    int r = 0;
    for (; r + 4 <= NL; r += 4) {
        a0 += lead[(long)r * D + d];
        a1 += lead[(long)(r + 1) * D + d];
        a2 += lead[(long)(r + 2) * D + d];
        a3 += lead[(long)(r + 3) * D + d];
    }
    for (; r < NL; ++r) a0 += lead[(long)r * D + d];
    hlead[d] = a0 + a1 + a2 + a3;
}

// fp32 per-graph segment sum (for x, init_feat)
__global__ __launch_bounds__(128)
void segsum_pg(const float* __restrict__ feat, const int* __restrict__ start,
               const float* __restrict__ addv, float* __restrict__ out) {
    int g = blockIdx.x;
    int d = threadIdx.x;
    int r0 = start[g], r1 = start[g + 1];
    float a0 = 0.f, a1 = 0.f, a2 = 0.f, a3 = 0.f;
    int r = r0;
    for (; r + 4 <= r1; r += 4) {
        a0 += feat[(long)r * D + d];
        a1 += feat[(long)(r + 1) * D + d];
        a2 += feat[(long)(r + 2) * D + d];
        a3 += feat[(long)(r + 3) * D + d];
    }
    for (; r < r1; ++r) a0 += feat[(long)r * D + d];
    float s = a0 + a1 + a2 + a3;
    if (addv) s += addv[d];
    out[(long)g * D + d] = s;
}

// bf16 per-graph segment sum (h stored as bf16 pairs, row = 64 uints)
__global__ __launch_bounds__(128)
void segsum_bf(const unsigned* __restrict__ hb, const int* __restrict__ start,
               float* __restrict__ out) {
    __shared__ float part[2][64][2];
    int g = blockIdx.x, t = threadIdx.x;
    int c = t & 63, half = t >> 6;
    int r0 = start[g], r1 = start[g + 1];
    float s0 = 0.f, s1 = 0.f, s2 = 0.f, s3 = 0.f;
    int r = r0 + half;
    for (; r + 2 < r1; r += 4) {
        unsigned a = hb[(long)r * 64 + c];
        unsigned bq = hb[(long)(r + 2) * 64 + c];
        s0 += bf_lo(a);  s1 += bf_hi(a);
        s2 += bf_lo(bq); s3 += bf_hi(bq);
    }
    if (r < r1) { unsigned a = hb[(long)r * 64 + c]; s0 += bf_lo(a); s1 += bf_hi(a); }
    part[half][c][0] = s0 + s2;
    part[half][c][1] = s1 + s3;
    __syncthreads();
    out[(long)g * D + t] = part[0][t >> 1][t & 1] + part[1][t >> 1][t & 1];
}

// ---------------------------------------------------------------- per-graph row matmul
__global__ __launch_bounds__(128)
void rowmat(const float* __restrict__ X, const float* __restrict__ Wm,
            const float* __restrict__ bias,
            const float* __restrict__ X2, const float* __restrict__ W2,
            float* __restrict__ out, int do_relu) {
    __shared__ float xs[D];
    __shared__ float xs2[D];
    int g = blockIdx.x;
    int d = threadIdx.x;
    xs[d] = X[(long)g * D + d];
    if (X2) xs2[d] = X2[(long)g * D + d];
    __syncthreads();
    float acc = bias ? bias[d] : 0.f;
    #pragma unroll 8
    for (int k = 0; k < D; ++k) acc += xs[k] * Wm[(long)k * D + d];
    if (X2) {
        #pragma unroll 8
        for (int k = 0; k < D; ++k) acc += xs2[k] * W2[(long)k * D + d];
    }
    out[(long)g * D + d] = do_relu ? fmaxf(acc, 0.f) : acc;
}

// ---------------------------------------------------------------- fused GIN layer (bf16 h)
#define TROWS 64
__global__ __launch_bounds__(256)
void layer_kernel(const unsigned* __restrict__ hb, const float* __restrict__ Wl,
                  const float* __restrict__ T, const int* __restrict__ gids,
                  const int* __restrict__ rowptr, const int* __restrict__ csr_src,
                  const float* __restrict__ eps_l, unsigned* __restrict__ houtb, int n) {
    __shared__ float Min[TROWS][D];
    int t = threadIdx.x;
    int wave = t >> 6, lane = t & 63;
    int rowBase = blockIdx.x * TROWS;
    float epsv = 1.0f + *eps_l;

    // Phase 1: CSR gather (bf16 loads, fp32 accumulate) -> LDS. 8 loads in flight.
    for (int i = 0; i < 16; ++i) {
        int rl = wave * 16 + i;
        int r = rowBase + rl;
        float sx = 0.f, sy = 0.f;
        if (r < n) {
            unsigned su = hb[(long)r * 64 + lane];
            float ax0 = epsv * bf_lo(su), ay0 = epsv * bf_hi(su);
            float ax1 = 0.f, ay1 = 0.f, ax2 = 0.f, ay2 = 0.f, ax3 = 0.f, ay3 = 0.f;
            int e = rowptr[r], e1 = rowptr[r + 1];
            for (; e + 8 <= e1; e += 8) {
                int s0 = csr_src[e+0], s1 = csr_src[e+1], s2 = csr_src[e+2], s3 = csr_src[e+3];
                int s4 = csr_src[e+4], s5 = csr_src[e+5], s6 = csr_src[e+6], s7 = csr_src[e+7];
                unsigned u0 = hb[(long)s0*64+lane], u1 = hb[(long)s1*64+lane];
                unsigned u2 = hb[(long)s2*64+lane], u3 = hb[(long)s3*64+lane];
                unsigned u4 = hb[(long)s4*64+lane], u5 = hb[(long)s5*64+lane];
                unsigned u6 = hb[(long)s6*64+lane], u7 = hb[(long)s7*64+lane];
                ax0 += bf_lo(u0); ay0 += bf_hi(u0);
                ax1 += bf_lo(u1); ay1 += bf_hi(u1);
                ax2 += bf_lo(u2); ay2 += bf_hi(u2);
                ax3 += bf_lo(u3); ay3 += bf_hi(u3);
                ax0 += bf_lo(u4); ay0 += bf_hi(u4);
                ax1 += bf_lo(u5); ay1 += bf_hi(u5);
                ax2 += bf_lo(u6); ay2 += bf_hi(u6);
                ax3 += bf_lo(u7); ay3 += bf_hi(u7);
            }
            for (; e + 2 <= e1; e += 2) {
                int s0 = csr_src[e], s1 = csr_src[e + 1];
                unsigned u0 = hb[(long)s0*64+lane], u1 = hb[(long)s1*64+lane];
                ax0 += bf_lo(u0); ay0 += bf_hi(u0);
                ax1 += bf_lo(u1); ay1 += bf_hi(u1);
            }
            if (e < e1) {
                unsigned u = hb[(long)csr_src[e]*64+lane];
                ax0 += bf_lo(u); ay0 += bf_hi(u);
            }
            sx = (ax0 + ax1) + (ax2 + ax3);
            sy = (ay0 + ay1) + (ay2 + ay3);
        }
        *(float2*)&Min[rl][2 * lane] = make_float2(sx, sy);
    }
    __syncthreads();

    // Phase 2: 64x128 tile matmul (fp32). Thread: rows r0..r0+7, cols c0..c0+3.
    int ty = t >> 5, tx = t & 31;
    int r0 = ty * 8, c0 = tx * 4;
    float acc[8][4];
    #pragma unroll
    for (int j = 0; j < 8; ++j)
        #pragma unroll
        for (int q = 0; q < 4; ++q) acc[j][q] = 0.f;

    for (int k = 0; k < D; k += 4) {
        float a_[8][4];
        #pragma unroll
        for (int j = 0; j < 8; ++j)
            *(float4*)a_[j] = *(const float4*)&Min[r0 + j][k];
        #pragma unroll
        for (int kk = 0; kk < 4; ++kk) {
            float4 wv = *(const float4*)(Wl + (long)(k + kk) * D + c0);
            #pragma unroll
            for (int j = 0; j < 8; ++j) {
                float av = a_[j][kk];
                acc[j][0] += av * wv.x;
                acc[j][1] += av * wv.y;
                acc[j][2] += av * wv.z;
                acc[j][3] += av * wv.w;
            }
        }
    }

    // Phase 3: add per-graph term, relu, pack bf16, store.
    #pragma unroll
    for (int j = 0; j < 8; ++j) {
        int r = rowBase + r0 + j;
        if (r < n) {
            int g = gids[r];
            float4 tv = *(const float4*)(T + (long)g * D + c0);
            float o0 = fmaxf(acc[j][0] + tv.x, 0.f);
            float o1 = fmaxf(acc[j][1] + tv.y, 0.f);
            float o2 = fmaxf(acc[j][2] + tv.z, 0.f);
            float o3 = fmaxf(acc[j][3] + tv.w, 0.f);
            *(uint2*)(houtb + (long)r * 64 + (c0 >> 1)) = make_uint2(pack2(o0, o1), pack2(o2, o3));
        }
    }
}

// ---------------------------------------------------------------- launch

static inline size_t align512(size_t x) { return (x + 511) & ~(size_t)511; }

extern "C" void kernel_launch(void* const* d_in, const int* in_sizes, int n_in,
                              void* d_out, int out_size, void* d_ws, size_t ws_size,
                              hipStream_t stream) {
    const float* x        = (const float*)d_in[0];
    const int*   src      = (const int*)d_in[1];
    const int*   dst      = (const int*)d_in[2];
    const int*   gids     = (const int*)d_in[3];
    const float* initf    = (const float*)d_in[4];
    const int*   init_gid = (const int*)d_in[5];
    const float* leadf    = (const float*)d_in[6];
    const float* W        = (const float*)d_in[7];
    const float* Wc       = (const float*)d_in[8];
    const float* b        = (const float*)d_in[9];
    const float* eps      = (const float*)d_in[10];
    const float* fc1_w    = (const float*)d_in[11];
    const float* fc1_b    = (const float*)d_in[12];
    const float* fc2_w    = (const float*)d_in[13];
    const float* fc2_b    = (const float*)d_in[14];
    float* out = (float*)d_out;

    const int N  = in_sizes[0] / D;
    const int E  = in_sizes[1];
    const int NI = in_sizes[4] / D;
    const int NL = in_sizes[6] / D;
    const int L  = in_sizes[10];
    const int C  = in_sizes[13] / D;
    const int G  = out_size / C;

    // workspace carve-up
    char* p = (char*)d_ws;
    unsigned* xb  = (unsigned*)p; p += align512((size_t)N * 64 * 4);   // x in bf16
    unsigned* hAb = (unsigned*)p; p += align512((size_t)N * 64 * 4);
    unsigned* hBb = (unsigned*)p; p += align512((size_t)N * 64 * 4);
    float* hg    = (float*)p; p += align512((size_t)G * D * 4);
    float* T     = (float*)p; p += align512((size_t)G * D * 4);
    float* ctx   = (float*)p; p += align512((size_t)G * D * 4);
    float* z     = (float*)p; p += align512((size_t)G * D * 4);
    float* hlead = (float*)p; p += align512((size_t)D * 4);
    int* rowptr  = (int*)p;   p += align512((size_t)(N + 1) * 4);
    int* cursor  = (int*)p;   p += align512((size_t)N * 4);
    int* csr     = (int*)p;   p += align512((size_t)E * 4);
    int* nstart  = (int*)p;   p += align512((size_t)(G + 1) * 4);
    int* istart  = (int*)p;   p += align512((size_t)(G + 1) * 4);
    int* psum    = (int*)p;   p += align512((size_t)512 * 4);
    (void)ws_size; (void)n_in;

    const int nb = (N + SCHUNK - 1) / SCHUNK;   // <= 128 for N <= 131072

    // ---- CSR build
    zero_u32<<<512, 256, 0, stream>>>((unsigned int*)cursor, N);
    count_deg<<<1024, 256, 0, stream>>>(dst, cursor, E);
    scan_part<<<nb, 256, 0, stream>>>(cursor, psum, N);
    scan_psum<<<1, 64, 0, stream>>>(psum, rowptr + N, nb);
    scan_scatter<<<nb, 256, 0, stream>>>(cursor, psum, rowptr, cursor, N);
    fill_csr<<<1024, 256, 0, stream>>>(src, dst, cursor, csr, E);

    // ---- bf16 copy of x
    f32_to_bf16<<<2048, 256, 0, stream>>>((const float4*)x, (uint2*)xb, (long)N * D / 4);

    // ---- per-graph row ranges (sorted gids)
    find_starts<<<(G + 256) / 256, 256, 0, stream>>>(gids, N, G, nstart);
    find_starts<<<(G + 256) / 256, 256, 0, stream>>>(init_gid, NI, G, istart);

    // ---- global context ctx[g] = segsum(init_feat)[g] + h_lead
    reduce_lead<<<1, D, 0, stream>>>(leadf, hlead, NL);
    segsum_pg<<<G, D, 0, stream>>>(initf, istart, hlead, ctx);

    // ---- initial h_global from x (fp32)
    segsum_pg<<<G, D, 0, stream>>>(x, nstart, (const float*)nullptr, hg);

    const unsigned* hcur = xb;
    unsigned* bufs[2] = { hAb, hBb };
    int layerBlocks = (N + TROWS - 1) / TROWS;
    for (int l = 0; l < L; ++l) {
        rowmat<<<G, D, 0, stream>>>(hg, W + (long)l * D * D, b + (long)l * D,
                                    ctx, Wc + (long)l * D * D, T, 0);
        unsigned* hnext = bufs[l & 1];
        layer_kernel<<<layerBlocks, 256, 0, stream>>>(hcur, W + (long)l * D * D, T,
                                                      gids, rowptr, csr,
                                                      eps + l, hnext, N);
        segsum_bf<<<G, D, 0, stream>>>(hnext, nstart, hg);
        hcur = hnext;
    }

    // ---- readout: out = relu(hg@fc1 + fc1_b) @ fc2 + fc2_b
    rowmat<<<G, D, 0, stream>>>(hg, fc1_w, fc1_b, (const float*)nullptr,
                                (const float*)nullptr, z, 1);
    rowmat<<<G, C, 0, stream>>>(z, fc2_w, fc2_b, (const float*)nullptr,
                                (const float*)nullptr, out, 0);
}

// Round 4
// 689.834 us; speedup vs baseline: 2.9270x; 1.3525x over previous
//
#include <hip/hip_runtime.h>

#define D 128

typedef short short8_t __attribute__((ext_vector_type(8)));
typedef float float4_t __attribute__((ext_vector_type(4)));

// ---------------------------------------------------------------- bf16 helpers
__device__ __forceinline__ float bf_lo(unsigned u) { return __uint_as_float(u << 16); }
__device__ __forceinline__ float bf_hi(unsigned u) { return __uint_as_float(u & 0xffff0000u); }
__device__ __forceinline__ unsigned to_bf1(float x) {           // RNE round to bf16
    unsigned b = __float_as_uint(x);
    return (b + 0x7fffu + ((b >> 16) & 1u)) >> 16;
}
__device__ __forceinline__ unsigned pack2(float a, float b) {
    return to_bf1(a) | (to_bf1(b) << 16);
}

// ---------------------------------------------------------------- utilities

__global__ void zero_u32(unsigned int* p, long n) {
    long i = (long)blockIdx.x * blockDim.x + threadIdx.x;
    long stride = (long)gridDim.x * blockDim.x;
    for (; i < n; i += stride) p[i] = 0u;
}

__global__ void f32_to_bf16(const float4* __restrict__ in, uint2* __restrict__ out, long n4) {
    long i = (long)blockIdx.x * blockDim.x + threadIdx.x;
    long stride = (long)gridDim.x * blockDim.x;
    for (; i < n4; i += stride) {
        float4 v = in[i];
        out[i] = make_uint2(pack2(v.x, v.y), pack2(v.z, v.w));
    }
}

// Pack W (L x 128 x 128 fp32) into MFMA B-fragment stream:
// Wpk[((l*8+t)*4+c)*64+lane] = uint4 of 8 bf16: W[k0+j][t*16+(lane&15)], k0=c*32+(lane>>4)*8
__global__ void wpack(const float* __restrict__ W, uint4* __restrict__ Wpk, int L_) {
    int id = blockIdx.x * blockDim.x + threadIdx.x;
    if (id >= L_ * 2048) return;
    int lane = id & 63, cc = (id >> 6) & 3, t = (id >> 8) & 7, l = id >> 11;
    int n = t * 16 + (lane & 15);
    int k0 = cc * 32 + (lane >> 4) * 8;
    const float* Wb = W + (long)l * D * D;
    unsigned u0 = pack2(Wb[(long)(k0 + 0) * D + n], Wb[(long)(k0 + 1) * D + n]);
    unsigned u1 = pack2(Wb[(long)(k0 + 2) * D + n], Wb[(long)(k0 + 3) * D + n]);
    unsigned u2 = pack2(Wb[(long)(k0 + 4) * D + n], Wb[(long)(k0 + 5) * D + n]);
    unsigned u3 = pack2(Wb[(long)(k0 + 6) * D + n], Wb[(long)(k0 + 7) * D + n]);
    Wpk[id] = make_uint4(u0, u1, u2, u3);
}

// ---------------------------------------------------------------- CSR build

__global__ void count_deg(const int* __restrict__ dst, int* __restrict__ deg, int E) {
    int i = blockIdx.x * blockDim.x + threadIdx.x;
    int stride = gridDim.x * blockDim.x;
    for (; i < E; i += stride) atomicAdd(&deg[dst[i]], 1);
}

#define SCHUNK 1024
__global__ __launch_bounds__(256)
void scan_part(const int* __restrict__ deg, int* __restrict__ psum, int n) {
    int b = blockIdx.x, t = threadIdx.x;
    int base = b * SCHUNK;
    int s = 0;
    for (int i = t; i < SCHUNK; i += 256) {
        int idx = base + i;
        if (idx < n) s += deg[idx];
    }
    for (int off = 32; off; off >>= 1) s += __shfl_down(s, off);
    __shared__ int ws[4];
    if ((t & 63) == 0) ws[t >> 6] = s;
    __syncthreads();
    if (t == 0) psum[b] = ws[0] + ws[1] + ws[2] + ws[3];
}

__global__ __launch_bounds__(64)
void scan_psum(int* __restrict__ psum, int* __restrict__ rowptrN, int nb) {
    int lane = threadIdx.x;
    int v0 = (lane < nb) ? psum[lane] : 0;
    int v1 = (lane + 64 < nb) ? psum[lane + 64] : 0;
    int x = v0;
    for (int off = 1; off < 64; off <<= 1) { int y = __shfl_up(x, off); if (lane >= off) x += y; }
    int total0 = __shfl(x, 63);
    int x1 = v1;
    for (int off = 1; off < 64; off <<= 1) { int y = __shfl_up(x1, off); if (lane >= off) x1 += y; }
    if (lane < nb) psum[lane] = x - v0;
    if (lane + 64 < nb) psum[lane + 64] = total0 + x1 - v1;
    if (lane == 63) rowptrN[0] = total0 + x1;
}

__global__ __launch_bounds__(256)
void scan_scatter(const int* __restrict__ deg, const int* __restrict__ psum,
                  int* __restrict__ rowptr, int* __restrict__ cursor, int n) {
    int b = blockIdx.x, t = threadIdx.x;
    int i0 = b * SCHUNK + t * 4;
    int d0 = 0, d1 = 0, d2 = 0, d3 = 0;
    if (i0     < n) d0 = deg[i0];
    if (i0 + 1 < n) d1 = deg[i0 + 1];
    if (i0 + 2 < n) d2 = deg[i0 + 2];
    if (i0 + 3 < n) d3 = deg[i0 + 3];
    int s = d0 + d1 + d2 + d3;
    __shared__ int sc[256];
    sc[t] = s; __syncthreads();
    for (int off = 1; off < 256; off <<= 1) {
        int v = (t >= off) ? sc[t - off] : 0;
        __syncthreads();
        sc[t] += v;
        __syncthreads();
    }
    int run = psum[b] + sc[t] - s;
    if (i0     < n) { rowptr[i0]     = run; cursor[i0]     = run; run += d0; }
    if (i0 + 1 < n) { rowptr[i0 + 1] = run; cursor[i0 + 1] = run; run += d1; }
    if (i0 + 2 < n) { rowptr[i0 + 2] = run; cursor[i0 + 2] = run; run += d2; }
    if (i0 + 3 < n) { rowptr[i0 + 3] = run; cursor[i0 + 3] = run; run += d3; }
}

__global__ void fill_csr(const int* __restrict__ src, const int* __restrict__ dst,
                         int* __restrict__ cursor, int* __restrict__ csr_src, int E) {
    int i = blockIdx.x * blockDim.x + threadIdx.x;
    int stride = gridDim.x * blockDim.x;
    for (; i < E; i += stride) {
        int p = atomicAdd(&cursor[dst[i]], 1);
        csr_src[p] = src[i];
    }
}

// ---------------------------------------------------------------- graph segment starts
__global__ void find_starts(const int* __restrict__ gids, int n, int G_,
                            int* __restrict__ start) {
    int g = blockIdx.x * blockDim.x + threadIdx.x;
    if (g > G_) return;
    if (g == G_) { start[g] = n; return; }
    int lo = 0, hi = n;
    while (lo < hi) { int mid = (lo + hi) >> 1; if (gids[mid] < g) lo = mid + 1; else hi = mid; }
    start[g] = lo;
}

// ---------------------------------------------------------------- small reductions

__global__ void reduce_lead(const float* __restrict__ lead, float* __restrict__ hlead, int NL) {
    int d = threadIdx.x;
    float a0 = 0.f, a1 = 0.f, a2 = 0.f, a3 = 0.f;
    int r = 0;
    for (; r + 4 <= NL; r += 4) {
        a0 += lead[(long)r * D + d];
        a1 += lead[(long)(r + 1) * D + d];
        a2 += lead[(long)(r + 2) * D + d];
        a3 += lead[(long)(r + 3) * D + d];
    }
    for (; r < NL; ++r) a0 += lead[(long)r * D + d];
    hlead[d] = a0 + a1 + a2 + a3;
}

// fp32 per-graph segment sum (for init_feat -> ctx, + hlead)
__global__ __launch_bounds__(128)
void segsum_pg(const float* __restrict__ feat, const int* __restrict__ start,
               const float* __restrict__ addv, float* __restrict__ out) {
    int g = blockIdx.x;
    int d = threadIdx.x;
    int r0 = start[g], r1 = start[g + 1];
    float a0 = 0.f, a1 = 0.f, a2 = 0.f, a3 = 0.f;
    int r = r0;
    for (; r + 4 <= r1; r += 4) {
        a0 += feat[(long)r * D + d];
        a1 += feat[(long)(r + 1) * D + d];
        a2 += feat[(long)(r + 2) * D + d];
        a3 += feat[(long)(r + 3) * D + d];
    }
    for (; r < r1; ++r) a0 += feat[(long)r * D + d];
    float s = a0 + a1 + a2 + a3;
    if (addv) s += addv[d];
    out[(long)g * D + d] = s;
}

// ---------------------------------------------------------------- fused per-graph term
// T[g] = segsum_bf(h)[g] @ Wl + ctx[g] @ Wcl + bl
__global__ __launch_bounds__(128)
void graph_term(const unsigned* __restrict__ hb, const int* __restrict__ start,
                const float* __restrict__ ctx, const float* __restrict__ Wl,
                const float* __restrict__ Wcl, const float* __restrict__ bl,
                float* __restrict__ T) {
    __shared__ float xs[D];
    __shared__ float cs[D];
    int g = blockIdx.x, tid = threadIdx.x;
    int r0 = start[g], r1 = start[g + 1];
    int c = tid >> 1;
    bool hi = tid & 1;
    float a0=0,a1=0,a2=0,a3=0,a4=0,a5=0,a6=0,a7=0;
    int r = r0;
    for (; r + 8 <= r1; r += 8) {
        unsigned u0 = hb[(long)(r+0)*64+c], u1 = hb[(long)(r+1)*64+c];
        unsigned u2 = hb[(long)(r+2)*64+c], u3 = hb[(long)(r+3)*64+c];
        unsigned u4 = hb[(long)(r+4)*64+c], u5 = hb[(long)(r+5)*64+c];
        unsigned u6 = hb[(long)(r+6)*64+c], u7 = hb[(long)(r+7)*64+c];
        a0 += hi ? bf_hi(u0) : bf_lo(u0);
        a1 += hi ? bf_hi(u1) : bf_lo(u1);
        a2 += hi ? bf_hi(u2) : bf_lo(u2);
        a3 += hi ? bf_hi(u3) : bf_lo(u3);
        a4 += hi ? bf_hi(u4) : bf_lo(u4);
        a5 += hi ? bf_hi(u5) : bf_lo(u5);
        a6 += hi ? bf_hi(u6) : bf_lo(u6);
        a7 += hi ? bf_hi(u7) : bf_lo(u7);
    }
    for (; r < r1; ++r) {
        unsigned u = hb[(long)r*64+c];
        a0 += hi ? bf_hi(u) : bf_lo(u);
    }
    xs[tid] = ((a0+a1)+(a2+a3)) + ((a4+a5)+(a6+a7));
    cs[tid] = ctx[(long)g * D + tid];
    __syncthreads();
    float p0=0,p1=0,p2=0,p3=0;
    for (int k = 0; k < D; k += 4) {
        p0 += xs[k]   * Wl[(long)k*D + tid];
        p1 += xs[k+1] * Wl[(long)(k+1)*D + tid];
        p2 += xs[k+2] * Wl[(long)(k+2)*D + tid];
        p3 += xs[k+3] * Wl[(long)(k+3)*D + tid];
    }
    for (int k = 0; k < D; k += 4) {
        p0 += cs[k]   * Wcl[(long)k*D + tid];
        p1 += cs[k+1] * Wcl[(long)(k+1)*D + tid];
        p2 += cs[k+2] * Wcl[(long)(k+2)*D + tid];
        p3 += cs[k+3] * Wcl[(long)(k+3)*D + tid];
    }
    T[(long)g * D + tid] = bl[tid] + (p0 + p1) + (p2 + p3);
}

// ---------------------------------------------------------------- readout
// out[g] = relu(segsum_bf(h)[g] @ fc1 + fc1_b) @ fc2 + fc2_b
__global__ __launch_bounds__(128)
void readout(const unsigned* __restrict__ hb, const int* __restrict__ start,
             const float* __restrict__ f1w, const float* __restrict__ f1b,
             const float* __restrict__ f2w, const float* __restrict__ f2b,
             float* __restrict__ out) {
    __shared__ float xs[D];
    __shared__ float zs[D];
    int g = blockIdx.x, tid = threadIdx.x;
    int r0 = start[g], r1 = start[g + 1];
    int c = tid >> 1;
    bool hi = tid & 1;
    float a0=0,a1=0,a2=0,a3=0;
    int r = r0;
    for (; r + 4 <= r1; r += 4) {
        unsigned u0 = hb[(long)(r+0)*64+c], u1 = hb[(long)(r+1)*64+c];
        unsigned u2 = hb[(long)(r+2)*64+c], u3 = hb[(long)(r+3)*64+c];
        a0 += hi ? bf_hi(u0) : bf_lo(u0);
        a1 += hi ? bf_hi(u1) : bf_lo(u1);
        a2 += hi ? bf_hi(u2) : bf_lo(u2);
        a3 += hi ? bf_hi(u3) : bf_lo(u3);
    }
    for (; r < r1; ++r) {
        unsigned u = hb[(long)r*64+c];
        a0 += hi ? bf_hi(u) : bf_lo(u);
    }
    xs[tid] = (a0+a1)+(a2+a3);
    __syncthreads();
    float p0=0,p1=0,p2=0,p3=0;
    for (int k = 0; k < D; k += 4) {
        p0 += xs[k]   * f1w[(long)k*D + tid];
        p1 += xs[k+1] * f1w[(long)(k+1)*D + tid];
        p2 += xs[k+2] * f1w[(long)(k+2)*D + tid];
        p3 += xs[k+3] * f1w[(long)(k+3)*D + tid];
    }
    zs[tid] = fmaxf(f1b[tid] + (p0+p1)+(p2+p3), 0.f);
    __syncthreads();
    float q0=0,q1=0,q2=0,q3=0;
    for (int k = 0; k < D; k += 4) {
        q0 += zs[k]   * f2w[(long)k*D + tid];
        q1 += zs[k+1] * f2w[(long)(k+1)*D + tid];
        q2 += zs[k+2] * f2w[(long)(k+2)*D + tid];
        q3 += zs[k+3] * f2w[(long)(k+3)*D + tid];
    }
    out[(long)g * D + tid] = f2b[tid] + (q0+q1)+(q2+q3);
}

// ---------------------------------------------------------------- fused GIN layer (bf16 h, MFMA)
#define TROWS 64
__global__ __launch_bounds__(256, 6)
void layer_kernel(const unsigned* __restrict__ hb, const uint4* __restrict__ Wpk_l,
                  const float* __restrict__ T, const int* __restrict__ gids,
                  const int* __restrict__ rowptr, const int* __restrict__ csr,
                  const float* __restrict__ eps_l, unsigned* __restrict__ houtb, int n) {
    // bf16 tile, row = 64 uints (+4 pad for conflict-free ds_read_b128)
    __shared__ __align__(16) unsigned Minb[TROWS][68];
    int tid = threadIdx.x;
    int w = tid >> 6, lane = tid & 63;
    int w16 = w * 16;
    int rowBase = blockIdx.x * TROWS;
    int rb = rowBase + w16;
    float epsv = 1.0f + *eps_l;

    // --- Phase 1: gather. One coalesced rowptr read gives all extents; edge
    //     indices fetched lane-parallel + shfl broadcast; next row prefetched.
    int rp = rb + lane; if (rp > n) rp = n;
    int evv = rowptr[rp];

    int e0 = __shfl(evv, 0);
    int e1 = __shfl(evv, 1);
    int idxv = (e0 + lane < e1) ? csr[e0 + lane] : 0;

    for (int i = 0; i < 16; ++i) {
        int r = rb + i;
        int deg = e1 - e0;
        int e0n = __shfl(evv, i + 1);
        int e1n = __shfl(evv, i + 2);
        int idxn = (e0n + lane < e1n) ? csr[e0n + lane] : 0;
        float sx = 0.f, sy = 0.f;
        if (r < n) {
            unsigned su = hb[(long)r * 64 + lane];
            float ax0 = epsv * bf_lo(su), ay0 = epsv * bf_hi(su);
            float ax1=0,ay1=0,ax2=0,ay2=0,ax3=0,ay3=0;
            int iv = idxv;
            int base = 0;
            while (true) {
                int m = deg - base; if (m > 64) m = 64;
                int j = 0;
                for (; j + 8 <= m; j += 8) {
                    int s0=__shfl(iv,j+0), s1=__shfl(iv,j+1), s2=__shfl(iv,j+2), s3=__shfl(iv,j+3);
                    int s4=__shfl(iv,j+4), s5=__shfl(iv,j+5), s6=__shfl(iv,j+6), s7=__shfl(iv,j+7);
                    unsigned u0=hb[(long)s0*64+lane], u1=hb[(long)s1*64+lane];
                    unsigned u2=hb[(long)s2*64+lane], u3=hb[(long)s3*64+lane];
                    unsigned u4=hb[(long)s4*64+lane], u5=hb[(long)s5*64+lane];
                    unsigned u6=hb[(long)s6*64+lane], u7=hb[(long)s7*64+lane];
                    ax0+=bf_lo(u0); ay0+=bf_hi(u0); ax1+=bf_lo(u1); ay1+=bf_hi(u1);
                    ax2+=bf_lo(u2); ay2+=bf_hi(u2); ax3+=bf_lo(u3); ay3+=bf_hi(u3);
                    ax0+=bf_lo(u4); ay0+=bf_hi(u4); ax1+=bf_lo(u5); ay1+=bf_hi(u5);
                    ax2+=bf_lo(u6); ay2+=bf_hi(u6); ax3+=bf_lo(u7); ay3+=bf_hi(u7);
                }
                for (; j < m; ++j) {
                    int s = __shfl(iv, j);
                    unsigned u = hb[(long)s * 64 + lane];
                    ax0 += bf_lo(u); ay0 += bf_hi(u);
                }
                base += 64;
                if (base >= deg) break;
                int mm = deg - base;
                iv = (lane < mm) ? csr[e0 + base + lane] : 0;
            }
            sx = (ax0 + ax1) + (ax2 + ax3);
            sy = (ay0 + ay1) + (ay2 + ay3);
        }
        Minb[w16 + i][lane] = pack2(sx, sy);
        e0 = e0n; e1 = e1n; idxv = idxn;
    }
    // No barrier: each wave's rows are private (gather, A-read, epilogue, store).

    // --- Phase 2: MFMA 16x16x32 bf16. Wave = 16 rows x 128 cols (8 n-tiles).
    int m_ = lane & 15, quad = lane >> 4;
    float4_t acc[8];
    #pragma unroll
    for (int tt = 0; tt < 8; ++tt) { acc[tt][0]=0.f; acc[tt][1]=0.f; acc[tt][2]=0.f; acc[tt][3]=0.f; }

    #pragma unroll
    for (int cc = 0; cc < 4; ++cc) {
        short8_t af = *(const short8_t*)&Minb[w16 + m_][cc * 16 + quad * 4];
        #pragma unroll
        for (int tt = 0; tt < 8; ++tt) {
            short8_t bf = *(const short8_t*)&Wpk_l[(tt * 4 + cc) * 64 + lane];
            acc[tt] = __builtin_amdgcn_mfma_f32_16x16x32_bf16(af, bf, acc[tt], 0, 0, 0);
        }
    }

    // --- Phase 3: + T[gid], relu, pack bf16 via shfl_xor, stage in LDS, store.
    int gq[4];
    #pragma unroll
    for (int reg = 0; reg < 4; ++reg) {
        int r = rb + quad * 4 + reg;
        gq[reg] = (r < n) ? gids[r] : 0;
    }
    #pragma unroll
    for (int tt = 0; tt < 8; ++tt) {
        int col = tt * 16 + m_;
        #pragma unroll
        for (int reg = 0; reg < 4; ++reg) {
            float v = acc[tt][reg] + T[(long)gq[reg] * D + col];
            v = fmaxf(v, 0.f);
            float v2 = __shfl_xor(v, 1);
            if (!(lane & 1)) Minb[w16 + quad * 4 + reg][tt * 8 + (m_ >> 1)] = pack2(v, v2);
        }
    }
    #pragma unroll
    for (int rr = 0; rr < 4; ++rr) {
        int lrow = rr * 4 + (lane >> 4);
        int r = rowBase + w16 + lrow;
        if (r < n) {
            uint4 v = *(const uint4*)&Minb[w16 + lrow][(lane & 15) * 4];
            *(uint4*)&houtb[(long)r * 64 + (lane & 15) * 4] = v;
        }
    }
}

// ---------------------------------------------------------------- launch

static inline size_t align512(size_t x) { return (x + 511) & ~(size_t)511; }

extern "C" void kernel_launch(void* const* d_in, const int* in_sizes, int n_in,
                              void* d_out, int out_size, void* d_ws, size_t ws_size,
                              hipStream_t stream) {
    const float* x        = (const float*)d_in[0];
    const int*   src      = (const int*)d_in[1];
    const int*   dst      = (const int*)d_in[2];
    const int*   gids     = (const int*)d_in[3];
    const float* initf    = (const float*)d_in[4];
    const int*   init_gid = (const int*)d_in[5];
    const float* leadf    = (const float*)d_in[6];
    const float* W        = (const float*)d_in[7];
    const float* Wc       = (const float*)d_in[8];
    const float* b        = (const float*)d_in[9];
    const float* eps      = (const float*)d_in[10];
    const float* fc1_w    = (const float*)d_in[11];
    const float* fc1_b    = (const float*)d_in[12];
    const float* fc2_w    = (const float*)d_in[13];
    const float* fc2_b    = (const float*)d_in[14];
    float* out = (float*)d_out;

    const int N  = in_sizes[0] / D;
    const int E  = in_sizes[1];
    const int NI = in_sizes[4] / D;
    const int NL = in_sizes[6] / D;
    const int L  = in_sizes[10];
    (void)NI;

    // workspace carve-up
    char* p = (char*)d_ws;
    unsigned* xb  = (unsigned*)p; p += align512((size_t)N * 64 * 4);
    unsigned* hAb = (unsigned*)p; p += align512((size_t)N * 64 * 4);
    unsigned* hBb = (unsigned*)p; p += align512((size_t)N * 64 * 4);
    const int G = 1024;
    float* T     = (float*)p; p += align512((size_t)G * D * 4);
    float* ctx   = (float*)p; p += align512((size_t)G * D * 4);
    float* hlead = (float*)p; p += align512((size_t)D * 4);
    int* rowptr  = (int*)p;   p += align512((size_t)(N + 1) * 4);
    int* cursor  = (int*)p;   p += align512((size_t)N * 4);
    int* csr     = (int*)p;   p += align512((size_t)E * 4);
    int* nstart  = (int*)p;   p += align512((size_t)(G + 1) * 4);
    int* istart  = (int*)p;   p += align512((size_t)(G + 1) * 4);
    int* psum    = (int*)p;   p += align512((size_t)512 * 4);
    uint4* Wpk   = (uint4*)p; p += align512((size_t)L * 2048 * 16);
    (void)ws_size; (void)n_in;

    const int nb = (N + SCHUNK - 1) / SCHUNK;

    // ---- CSR build
    zero_u32<<<512, 256, 0, stream>>>((unsigned int*)cursor, N);
    count_deg<<<1024, 256, 0, stream>>>(dst, cursor, E);
    scan_part<<<nb, 256, 0, stream>>>(cursor, psum, N);
    scan_psum<<<1, 64, 0, stream>>>(psum, rowptr + N, nb);
    scan_scatter<<<nb, 256, 0, stream>>>(cursor, psum, rowptr, cursor, N);
    fill_csr<<<1024, 256, 0, stream>>>(src, dst, cursor, csr, E);

    // ---- bf16 copy of x; packed W fragments
    f32_to_bf16<<<2048, 256, 0, stream>>>((const float4*)x, (uint2*)xb, (long)N * D / 4);
    wpack<<<(L * 2048 + 255) / 256, 256, 0, stream>>>(W, Wpk, L);

    // ---- per-graph row ranges (sorted gids)
    find_starts<<<(G + 256) / 256, 256, 0, stream>>>(gids, N, G, nstart);
    find_starts<<<(G + 256) / 256, 256, 0, stream>>>(init_gid, in_sizes[4] / D, G, istart);

    // ---- global context ctx[g] = segsum(init_feat)[g] + h_lead
    reduce_lead<<<1, D, 0, stream>>>(leadf, hlead, NL);
    segsum_pg<<<G, D, 0, stream>>>(initf, istart, hlead, ctx);

    const unsigned* hcur = xb;
    unsigned* bufs[2] = { hAb, hBb };
    int layerBlocks = (N + TROWS - 1) / TROWS;
    for (int l = 0; l < L; ++l) {
        graph_term<<<G, D, 0, stream>>>(hcur, nstart, ctx, W + (long)l * D * D,
                                        Wc + (long)l * D * D, b + (long)l * D, T);
        unsigned* hnext = bufs[l & 1];
        layer_kernel<<<layerBlocks, 256, 0, stream>>>(hcur, Wpk + (size_t)l * 2048, T,
                                                      gids, rowptr, csr,
                                                      eps + l, hnext, N);
        hcur = hnext;
    }

    // ---- readout
    readout<<<G, D, 0, stream>>>(hcur, nstart, fc1_w, fc1_b, fc2_w, fc2_b, out);
}

// Round 5
// 534.893 us; speedup vs baseline: 3.7748x; 1.2897x over previous
//
#include <hip/hip_runtime.h>

#define D 128

typedef short short8_t __attribute__((ext_vector_type(8)));
typedef float float4_t __attribute__((ext_vector_type(4)));

// CSR-build bucketing: bucket = dst >> 8 (256 nodes/bucket), NB <= 512
#define BSH 8
#define BSZ 256
#define NBLK_A 256          // blocks for histogram/scatter passes

// ---------------------------------------------------------------- bf16 helpers
__device__ __forceinline__ float bf_lo(unsigned u) { return __uint_as_float(u << 16); }
__device__ __forceinline__ float bf_hi(unsigned u) { return __uint_as_float(u & 0xffff0000u); }
__device__ __forceinline__ unsigned to_bf1(float x) {           // RNE round to bf16
    unsigned b = __float_as_uint(x);
    return (b + 0x7fffu + ((b >> 16) & 1u)) >> 16;
}
__device__ __forceinline__ unsigned pack2(float a, float b) {
    return to_bf1(a) | (to_bf1(b) << 16);
}

// ---------------------------------------------------------------- utilities

__global__ void f32_to_bf16(const float4* __restrict__ in, uint2* __restrict__ out, long n4) {
    long i = (long)blockIdx.x * blockDim.x + threadIdx.x;
    long stride = (long)gridDim.x * blockDim.x;
    for (; i < n4; i += stride) {
        float4 v = in[i];
        out[i] = make_uint2(pack2(v.x, v.y), pack2(v.z, v.w));
    }
}

// Pack W (L x 128 x 128 fp32) into MFMA B-fragment stream.
__global__ void wpack(const float* __restrict__ W, uint4* __restrict__ Wpk, int L_) {
    int id = blockIdx.x * blockDim.x + threadIdx.x;
    if (id >= L_ * 2048) return;
    int lane = id & 63, cc = (id >> 6) & 3, t = (id >> 8) & 7, l = id >> 11;
    int n = t * 16 + (lane & 15);
    int k0 = cc * 32 + (lane >> 4) * 8;
    const float* Wb = W + (long)l * D * D;
    unsigned u0 = pack2(Wb[(long)(k0 + 0) * D + n], Wb[(long)(k0 + 1) * D + n]);
    unsigned u1 = pack2(Wb[(long)(k0 + 2) * D + n], Wb[(long)(k0 + 3) * D + n]);
    unsigned u2 = pack2(Wb[(long)(k0 + 4) * D + n], Wb[(long)(k0 + 5) * D + n]);
    unsigned u3 = pack2(Wb[(long)(k0 + 6) * D + n], Wb[(long)(k0 + 7) * D + n]);
    Wpk[id] = make_uint4(u0, u1, u2, u3);
}

// ---------------------------------------------------------------- CSR build (bucketed)

// A1: per-block histogram of dst buckets -> Hist[blk*512 + bkt]
__global__ __launch_bounds__(256)
void csr_hist(const int* __restrict__ dst, int* __restrict__ Hist, int E_, int chunk) {
    __shared__ int h[512];
    int b = blockIdx.x, t = threadIdx.x;
    h[t] = 0; h[t + 256] = 0;
    __syncthreads();
    int base = b * chunk;
    int end = base + chunk; if (end > E_) end = E_;
    for (int i = base + t; i < end; i += 256)
        atomicAdd(&h[dst[i] >> BSH], 1);
    __syncthreads();
    Hist[b * 512 + t] = h[t];
    Hist[b * 512 + t + 256] = h[t + 256];
}

// A2a: for each bucket, exclusive-scan Hist[:, bkt] across the NBLK_A blocks; total -> Tot[bkt]
__global__ __launch_bounds__(256)
void csr_scan_blocks(int* __restrict__ Hist, int* __restrict__ Tot) {
    __shared__ int sc[256];
    int bkt = blockIdx.x, t = threadIdx.x;
    int v = Hist[t * 512 + bkt];
    sc[t] = v; __syncthreads();
    for (int off = 1; off < 256; off <<= 1) {
        int u = (t >= off) ? sc[t - off] : 0;
        __syncthreads();
        sc[t] += u;
        __syncthreads();
    }
    Hist[t * 512 + bkt] = sc[t] - v;          // exclusive
    if (t == 255) Tot[bkt] = sc[255];
}

// A2b: exclusive scan of Tot[0..NB) -> Base[0..NB]
__global__ __launch_bounds__(512)
void csr_scan_base(const int* __restrict__ Tot, int* __restrict__ Base, int NB) {
    __shared__ int sc[512];
    int t = threadIdx.x;
    int v = (t < NB) ? Tot[t] : 0;
    sc[t] = v; __syncthreads();
    for (int off = 1; off < 512; off <<= 1) {
        int u = (t >= off) ? sc[t - off] : 0;
        __syncthreads();
        sc[t] += u;
        __syncthreads();
    }
    Base[t] = sc[t] - v;
    if (t == NB - 1) Base[NB] = sc[t];
}

// A3: scatter packed edges (src | dst_local<<24) into bucket-major EdgeBuf
__global__ __launch_bounds__(256)
void csr_scatter(const int* __restrict__ src, const int* __restrict__ dst,
                 const int* __restrict__ Hist, const int* __restrict__ Base,
                 unsigned* __restrict__ EdgeBuf, int E_, int chunk) {
    __shared__ int cur[512];
    int b = blockIdx.x, t = threadIdx.x;
    cur[t]       = Base[t]       + Hist[b * 512 + t];
    cur[t + 256] = Base[t + 256] + Hist[b * 512 + t + 256];
    __syncthreads();
    int base = b * chunk;
    int end = base + chunk; if (end > E_) end = E_;
    for (int i = base + t; i < end; i += 256) {
        int s = src[i], dd = dst[i];
        int p = atomicAdd(&cur[dd >> BSH], 1);
        EdgeBuf[p] = (unsigned)s | ((unsigned)(dd & (BSZ - 1)) << 24);
    }
}

// B: per-bucket CSR: count deg in LDS, scan, write rowptr slice, fill csr slice
__global__ __launch_bounds__(256)
void csr_fill(const unsigned* __restrict__ EdgeBuf, const int* __restrict__ Base,
              int* __restrict__ rowptr, int* __restrict__ csr, int N_, int E_) {
    __shared__ int deg[256];
    __shared__ int cur[256];
    int b = blockIdx.x, t = threadIdx.x;
    int e0 = Base[b], e1 = Base[b + 1];
    deg[t] = 0;
    __syncthreads();
    for (int i = e0 + t; i < e1; i += 256)
        atomicAdd(&deg[EdgeBuf[i] >> 24], 1);
    __syncthreads();
    int v = deg[t];
    // exclusive scan over 256 (reuse deg as scan array via cur staging)
    cur[t] = v; __syncthreads();
    for (int off = 1; off < 256; off <<= 1) {
        int u = (t >= off) ? cur[t - off] : 0;
        __syncthreads();
        cur[t] += u;
        __syncthreads();
    }
    int excl = cur[t] - v;
    int node = b * BSZ + t;
    if (node < N_) rowptr[node] = e0 + excl;
    cur[t] = e0 + excl;      // absolute cursor
    __syncthreads();
    for (int i = e0 + t; i < e1; i += 256) {
        unsigned ev = EdgeBuf[i];
        int p = atomicAdd(&cur[ev >> 24], 1);
        csr[p] = (int)(ev & 0x00FFFFFFu);
    }
    if (b == 0 && t == 0) rowptr[N_] = E_;
}

// ---------------------------------------------------------------- graph segment starts
__global__ void find_starts(const int* __restrict__ gids, int n, int G_,
                            int* __restrict__ start) {
    int g = blockIdx.x * blockDim.x + threadIdx.x;
    if (g > G_) return;
    if (g == G_) { start[g] = n; return; }
    int lo = 0, hi = n;
    while (lo < hi) { int mid = (lo + hi) >> 1; if (gids[mid] < g) lo = mid + 1; else hi = mid; }
    start[g] = lo;
}

// ---------------------------------------------------------------- small reductions

__global__ void reduce_lead(const float* __restrict__ lead, float* __restrict__ hlead, int NL) {
    int d = threadIdx.x;
    float a0 = 0.f, a1 = 0.f, a2 = 0.f, a3 = 0.f;
    int r = 0;
    for (; r + 4 <= NL; r += 4) {
        a0 += lead[(long)r * D + d];
        a1 += lead[(long)(r + 1) * D + d];
        a2 += lead[(long)(r + 2) * D + d];
        a3 += lead[(long)(r + 3) * D + d];
    }
    for (; r < NL; ++r) a0 += lead[(long)r * D + d];
    hlead[d] = a0 + a1 + a2 + a3;
}

// fp32 per-graph segment sum (for init_feat -> ctx, + hlead)
__global__ __launch_bounds__(128)
void segsum_pg(const float* __restrict__ feat, const int* __restrict__ start,
               const float* __restrict__ addv, float* __restrict__ out) {
    int g = blockIdx.x;
    int d = threadIdx.x;
    int r0 = start[g], r1 = start[g + 1];
    float a0 = 0.f, a1 = 0.f, a2 = 0.f, a3 = 0.f;
    int r = r0;
    for (; r + 4 <= r1; r += 4) {
        a0 += feat[(long)r * D + d];
        a1 += feat[(long)(r + 1) * D + d];
        a2 += feat[(long)(r + 2) * D + d];
        a3 += feat[(long)(r + 3) * D + d];
    }
    for (; r < r1; ++r) a0 += feat[(long)r * D + d];
    float s = a0 + a1 + a2 + a3;
    if (addv) s += addv[d];
    out[(long)g * D + d] = s;
}

// ---------------------------------------------------------------- fused per-graph term
// T[g] = segsum_bf(h)[g] @ Wl + ctx[g] @ Wcl + bl
__global__ __launch_bounds__(128)
void graph_term(const unsigned* __restrict__ hb, const int* __restrict__ start,
                const float* __restrict__ ctx, const float* __restrict__ Wl,
                const float* __restrict__ Wcl, const float* __restrict__ bl,
                float* __restrict__ T) {
    __shared__ float xs[D];
    __shared__ float cs[D];
    int g = blockIdx.x, tid = threadIdx.x;
    int r0 = start[g], r1 = start[g + 1];
    int c = tid >> 1;
    bool hi = tid & 1;
    float a0=0,a1=0,a2=0,a3=0,a4=0,a5=0,a6=0,a7=0;
    int r = r0;
    for (; r + 8 <= r1; r += 8) {
        unsigned u0 = hb[(long)(r+0)*64+c], u1 = hb[(long)(r+1)*64+c];
        unsigned u2 = hb[(long)(r+2)*64+c], u3 = hb[(long)(r+3)*64+c];
        unsigned u4 = hb[(long)(r+4)*64+c], u5 = hb[(long)(r+5)*64+c];
        unsigned u6 = hb[(long)(r+6)*64+c], u7 = hb[(long)(r+7)*64+c];
        a0 += hi ? bf_hi(u0) : bf_lo(u0);
        a1 += hi ? bf_hi(u1) : bf_lo(u1);
        a2 += hi ? bf_hi(u2) : bf_lo(u2);
        a3 += hi ? bf_hi(u3) : bf_lo(u3);
        a4 += hi ? bf_hi(u4) : bf_lo(u4);
        a5 += hi ? bf_hi(u5) : bf_lo(u5);
        a6 += hi ? bf_hi(u6) : bf_lo(u6);
        a7 += hi ? bf_hi(u7) : bf_lo(u7);
    }
    for (; r < r1; ++r) {
        unsigned u = hb[(long)r*64+c];
        a0 += hi ? bf_hi(u) : bf_lo(u);
    }
    xs[tid] = ((a0+a1)+(a2+a3)) + ((a4+a5)+(a6+a7));
    cs[tid] = ctx[(long)g * D + tid];
    __syncthreads();
    float p0=0,p1=0,p2=0,p3=0;
    for (int k = 0; k < D; k += 4) {
        p0 += xs[k]   * Wl[(long)k*D + tid];
        p1 += xs[k+1] * Wl[(long)(k+1)*D + tid];
        p2 += xs[k+2] * Wl[(long)(k+2)*D + tid];
        p3 += xs[k+3] * Wl[(long)(k+3)*D + tid];
    }
    for (int k = 0; k < D; k += 4) {
        p0 += cs[k]   * Wcl[(long)k*D + tid];
        p1 += cs[k+1] * Wcl[(long)(k+1)*D + tid];
        p2 += cs[k+2] * Wcl[(long)(k+2)*D + tid];
        p3 += cs[k+3] * Wcl[(long)(k+3)*D + tid];
    }
    T[(long)g * D + tid] = bl[tid] + (p0 + p1) + (p2 + p3);
}

// ---------------------------------------------------------------- readout
__global__ __launch_bounds__(128)
void readout(const unsigned* __restrict__ hb, const int* __restrict__ start,
             const float* __restrict__ f1w, const float* __restrict__ f1b,
             const float* __restrict__ f2w, const float* __restrict__ f2b,
             float* __restrict__ out) {
    __shared__ float xs[D];
    __shared__ float zs[D];
    int g = blockIdx.x, tid = threadIdx.x;
    int r0 = start[g], r1 = start[g + 1];
    int c = tid >> 1;
    bool hi = tid & 1;
    float a0=0,a1=0,a2=0,a3=0;
    int r = r0;
    for (; r + 4 <= r1; r += 4) {
        unsigned u0 = hb[(long)(r+0)*64+c], u1 = hb[(long)(r+1)*64+c];
        unsigned u2 = hb[(long)(r+2)*64+c], u3 = hb[(long)(r+3)*64+c];
        a0 += hi ? bf_hi(u0) : bf_lo(u0);
        a1 += hi ? bf_hi(u1) : bf_lo(u1);
        a2 += hi ? bf_hi(u2) : bf_lo(u2);
        a3 += hi ? bf_hi(u3) : bf_lo(u3);
    }
    for (; r < r1; ++r) {
        unsigned u = hb[(long)r*64+c];
        a0 += hi ? bf_hi(u) : bf_lo(u);
    }
    xs[tid] = (a0+a1)+(a2+a3);
    __syncthreads();
    float p0=0,p1=0,p2=0,p3=0;
    for (int k = 0; k < D; k += 4) {
        p0 += xs[k]   * f1w[(long)k*D + tid];
        p1 += xs[k+1] * f1w[(long)(k+1)*D + tid];
        p2 += xs[k+2] * f1w[(long)(k+2)*D + tid];
        p3 += xs[k+3] * f1w[(long)(k+3)*D + tid];
    }
    zs[tid] = fmaxf(f1b[tid] + (p0+p1)+(p2+p3), 0.f);
    __syncthreads();
    float q0=0,q1=0,q2=0,q3=0;
    for (int k = 0; k < D; k += 4) {
        q0 += zs[k]   * f2w[(long)k*D + tid];
        q1 += zs[k+1] * f2w[(long)(k+1)*D + tid];
        q2 += zs[k+2] * f2w[(long)(k+2)*D + tid];
        q3 += zs[k+3] * f2w[(long)(k+3)*D + tid];
    }
    out[(long)g * D + tid] = f2b[tid] + (q0+q1)+(q2+q3);
}

// ---------------------------------------------------------------- fused GIN layer (bf16 h, MFMA)
#define TROWS 64
__global__ __launch_bounds__(256, 6)
void layer_kernel(const unsigned* __restrict__ hb, const uint4* __restrict__ Wpk_l,
                  const float* __restrict__ T, const int* __restrict__ gids,
                  const int* __restrict__ rowptr, const int* __restrict__ csr,
                  const float* __restrict__ eps_l, unsigned* __restrict__ houtb, int n) {
    __shared__ __align__(16) unsigned Minb[TROWS][68];
    int tid = threadIdx.x;
    int w = tid >> 6, lane = tid & 63;
    int w16 = w * 16;
    int rowBase = blockIdx.x * TROWS;
    int rb = rowBase + w16;
    float epsv = 1.0f + *eps_l;

    int rp = rb + lane; if (rp > n) rp = n;
    int evv = rowptr[rp];

    int e0 = __shfl(evv, 0);
    int e1 = __shfl(evv, 1);
    int idxv = (e0 + lane < e1) ? csr[e0 + lane] : 0;

    for (int i = 0; i < 16; ++i) {
        int r = rb + i;
        int deg = e1 - e0;
        int e0n = __shfl(evv, i + 1);
        int e1n = __shfl(evv, i + 2);
        int idxn = (e0n + lane < e1n) ? csr[e0n + lane] : 0;
        float sx = 0.f, sy = 0.f;
        if (r < n) {
            unsigned su = hb[(long)r * 64 + lane];
            float ax0 = epsv * bf_lo(su), ay0 = epsv * bf_hi(su);
            float ax1=0,ay1=0,ax2=0,ay2=0,ax3=0,ay3=0;
            int iv = idxv;
            int base = 0;
            while (true) {
                int m = deg - base; if (m > 64) m = 64;
                int j = 0;
                for (; j + 8 <= m; j += 8) {
                    int s0=__shfl(iv,j+0), s1=__shfl(iv,j+1), s2=__shfl(iv,j+2), s3=__shfl(iv,j+3);
                    int s4=__shfl(iv,j+4), s5=__shfl(iv,j+5), s6=__shfl(iv,j+6), s7=__shfl(iv,j+7);
                    unsigned u0=hb[(long)s0*64+lane], u1=hb[(long)s1*64+lane];
                    unsigned u2=hb[(long)s2*64+lane], u3=hb[(long)s3*64+lane];
                    unsigned u4=hb[(long)s4*64+lane], u5=hb[(long)s5*64+lane];
                    unsigned u6=hb[(long)s6*64+lane], u7=hb[(long)s7*64+lane];
                    ax0+=bf_lo(u0); ay0+=bf_hi(u0); ax1+=bf_lo(u1); ay1+=bf_hi(u1);
                    ax2+=bf_lo(u2); ay2+=bf_hi(u2); ax3+=bf_lo(u3); ay3+=bf_hi(u3);
                    ax0+=bf_lo(u4); ay0+=bf_hi(u4); ax1+=bf_lo(u5); ay1+=bf_hi(u5);
                    ax2+=bf_lo(u6); ay2+=bf_hi(u6); ax3+=bf_lo(u7); ay3+=bf_hi(u7);
                }
                for (; j < m; ++j) {
                    int s = __shfl(iv, j);
                    unsigned u = hb[(long)s * 64 + lane];
                    ax0 += bf_lo(u); ay0 += bf_hi(u);
                }
                base += 64;
                if (base >= deg) break;
                int mm = deg - base;
                iv = (lane < mm) ? csr[e0 + base + lane] : 0;
            }
            sx = (ax0 + ax1) + (ax2 + ax3);
            sy = (ay0 + ay1) + (ay2 + ay3);
        }
        Minb[w16 + i][lane] = pack2(sx, sy);
        e0 = e0n; e1 = e1n; idxv = idxn;
    }
    // No barrier: each wave's rows are private.

    int m_ = lane & 15, quad = lane >> 4;
    float4_t acc[8];
    #pragma unroll
    for (int tt = 0; tt < 8; ++tt) { acc[tt][0]=0.f; acc[tt][1]=0.f; acc[tt][2]=0.f; acc[tt][3]=0.f; }

    #pragma unroll
    for (int cc = 0; cc < 4; ++cc) {
        short8_t af = *(const short8_t*)&Minb[w16 + m_][cc * 16 + quad * 4];
        #pragma unroll
        for (int tt = 0; tt < 8; ++tt) {
            short8_t bf = *(const short8_t*)&Wpk_l[(tt * 4 + cc) * 64 + lane];
            acc[tt] = __builtin_amdgcn_mfma_f32_16x16x32_bf16(af, bf, acc[tt], 0, 0, 0);
        }
    }

    int gq[4];
    #pragma unroll
    for (int reg = 0; reg < 4; ++reg) {
        int r = rb + quad * 4 + reg;
        gq[reg] = (r < n) ? gids[r] : 0;
    }
    #pragma unroll
    for (int tt = 0; tt < 8; ++tt) {
        int col = tt * 16 + m_;
        #pragma unroll
        for (int reg = 0; reg < 4; ++reg) {
            float v = acc[tt][reg] + T[(long)gq[reg] * D + col];
            v = fmaxf(v, 0.f);
            float v2 = __shfl_xor(v, 1);
            if (!(lane & 1)) Minb[w16 + quad * 4 + reg][tt * 8 + (m_ >> 1)] = pack2(v, v2);
        }
    }
    #pragma unroll
    for (int rr = 0; rr < 4; ++rr) {
        int lrow = rr * 4 + (lane >> 4);
        int r = rowBase + w16 + lrow;
        if (r < n) {
            uint4 v = *(const uint4*)&Minb[w16 + lrow][(lane & 15) * 4];
            *(uint4*)&houtb[(long)r * 64 + (lane & 15) * 4] = v;
        }
    }
}

// ---------------------------------------------------------------- launch

static inline size_t align512(size_t x) { return (x + 511) & ~(size_t)511; }

extern "C" void kernel_launch(void* const* d_in, const int* in_sizes, int n_in,
                              void* d_out, int out_size, void* d_ws, size_t ws_size,
                              hipStream_t stream) {
    const float* x        = (const float*)d_in[0];
    const int*   src      = (const int*)d_in[1];
    const int*   dst      = (const int*)d_in[2];
    const int*   gids     = (const int*)d_in[3];
    const float* initf    = (const float*)d_in[4];
    const int*   init_gid = (const int*)d_in[5];
    const float* leadf    = (const float*)d_in[6];
    const float* W        = (const float*)d_in[7];
    const float* Wc       = (const float*)d_in[8];
    const float* b        = (const float*)d_in[9];
    const float* eps      = (const float*)d_in[10];
    const float* fc1_w    = (const float*)d_in[11];
    const float* fc1_b    = (const float*)d_in[12];
    const float* fc2_w    = (const float*)d_in[13];
    const float* fc2_b    = (const float*)d_in[14];
    float* out = (float*)d_out;

    const int N  = in_sizes[0] / D;
    const int E  = in_sizes[1];
    const int NL = in_sizes[6] / D;
    const int L  = in_sizes[10];

    // workspace carve-up
    char* p = (char*)d_ws;
    unsigned* xb  = (unsigned*)p; p += align512((size_t)N * 64 * 4);
    unsigned* hAb = (unsigned*)p; p += align512((size_t)N * 64 * 4);
    unsigned* hBb = (unsigned*)p; p += align512((size_t)N * 64 * 4);
    const int G = 1024;
    float* T     = (float*)p; p += align512((size_t)G * D * 4);
    float* ctx   = (float*)p; p += align512((size_t)G * D * 4);
    float* hlead = (float*)p; p += align512((size_t)D * 4);
    int* rowptr  = (int*)p;   p += align512((size_t)(N + 1) * 4);
    int* csr     = (int*)p;   p += align512((size_t)E * 4);
    unsigned* EdgeBuf = (unsigned*)p; p += align512((size_t)E * 4);
    int* Hist    = (int*)p;   p += align512((size_t)NBLK_A * 512 * 4);
    int* Tot     = (int*)p;   p += align512((size_t)520 * 4);
    int* Base    = (int*)p;   p += align512((size_t)520 * 4);
    int* nstart  = (int*)p;   p += align512((size_t)(G + 1) * 4);
    int* istart  = (int*)p;   p += align512((size_t)(G + 1) * 4);
    uint4* Wpk   = (uint4*)p; p += align512((size_t)L * 2048 * 16);
    (void)ws_size; (void)n_in;

    const int NB = (N + BSZ - 1) / BSZ;            // buckets (<=512 for N<=131072)
    const int chunk = (E + NBLK_A - 1) / NBLK_A;   // edges per A-pass block

    // ---- CSR build (bucketed, no global atomics, L2-local scatters)
    csr_hist<<<NBLK_A, 256, 0, stream>>>(dst, Hist, E, chunk);
    csr_scan_blocks<<<NB, 256, 0, stream>>>(Hist, Tot);
    csr_scan_base<<<1, 512, 0, stream>>>(Tot, Base, NB);
    csr_scatter<<<NBLK_A, 256, 0, stream>>>(src, dst, Hist, Base, EdgeBuf, E, chunk);
    csr_fill<<<NB, 256, 0, stream>>>(EdgeBuf, Base, rowptr, csr, N, E);

    // ---- bf16 copy of x; packed W fragments
    f32_to_bf16<<<2048, 256, 0, stream>>>((const float4*)x, (uint2*)xb, (long)N * D / 4);
    wpack<<<(L * 2048 + 255) / 256, 256, 0, stream>>>(W, Wpk, L);

    // ---- per-graph row ranges (sorted gids)
    find_starts<<<(G + 256) / 256, 256, 0, stream>>>(gids, N, G, nstart);
    find_starts<<<(G + 256) / 256, 256, 0, stream>>>(init_gid, in_sizes[4] / D, G, istart);

    // ---- global context ctx[g] = segsum(init_feat)[g] + h_lead
    reduce_lead<<<1, D, 0, stream>>>(leadf, hlead, NL);
    segsum_pg<<<G, D, 0, stream>>>(initf, istart, hlead, ctx);

    const unsigned* hcur = xb;
    unsigned* bufs[2] = { hAb, hBb };
    int layerBlocks = (N + TROWS - 1) / TROWS;
    for (int l = 0; l < L; ++l) {
        graph_term<<<G, D, 0, stream>>>(hcur, nstart, ctx, W + (long)l * D * D,
                                        Wc + (long)l * D * D, b + (long)l * D, T);
        unsigned* hnext = bufs[l & 1];
        layer_kernel<<<layerBlocks, 256, 0, stream>>>(hcur, Wpk + (size_t)l * 2048, T,
                                                      gids, rowptr, csr,
                                                      eps + l, hnext, N);
        hcur = hnext;
    }

    // ---- readout
    readout<<<G, D, 0, stream>>>(hcur, nstart, fc1_w, fc1_b, fc2_w, fc2_b, out);
}